// Round 8
// baseline (3286.946 us; speedup 1.0000x reference)
//
#include <hip/hip_runtime.h>

#define Bq 64
#define Sq 32
#define VFq 512
#define IFq 256
#define Fq 768
#define Uq 768
#define UNFq 6
#define L2E 1.44269504088896340736f

template <int CTRL>
__device__ __forceinline__ float dpp_add(float x) {
  int t = __builtin_amdgcn_update_dpp(0, __builtin_bit_cast(int, x), CTRL, 0xF, 0xF, true);
  return x + __builtin_bit_cast(float, t);
}
__device__ __forceinline__ float swz_add4(float x) {
  int t = __builtin_amdgcn_ds_swizzle(__builtin_bit_cast(int, x), 0x101F); // xor 4
  return x + __builtin_bit_cast(float, t);
}

// ---------------- K1: fold+transpose params, init misc ----------------
// P[u][v] = float4(-sigma*log2e, sigma*mu*log2e, w, w*erev)  (u = target, v = source)
__global__ __launch_bounds__(256) void k_prep(
    const float* __restrict__ smu, const float* __restrict__ ssig,
    const float* __restrict__ sw,  const float* __restrict__ ser,
    const float* __restrict__ rmu, const float* __restrict__ rsig,
    const float* __restrict__ rw,  const float* __restrict__ rer,
    const float* __restrict__ ts,
    float4* __restrict__ Ps, float4* __restrict__ Pr,
    float* __restrict__ iel, unsigned* __restrict__ flags)
{
  int bid = blockIdx.x, tid = threadIdx.x;
  if (bid < 1152) {
    int set = bid / 576, tile = bid % 576;
    int tv = tile / 24, tu = tile % 24;
    const float* Amu = set ? rmu : smu;
    const float* Asg = set ? rsig : ssig;
    const float* Aw  = set ? rw  : sw;
    const float* Aer = set ? rer : ser;
    float4* P = set ? Pr : Ps;
    __shared__ float4 tl[32][33];
    int cu = tid & 31, r0 = tid >> 5;            // 32 cols x 8 rows
    for (int rr = 0; rr < 32; rr += 8) {
      int v = tv*32 + r0 + rr, u = tu*32 + cu;
      int idx = v*Uq + u;                         // source-major input layout
      float sg = Asg[idx], m = Amu[idx], ww = Aw[idx], er = Aer[idx];
      tl[cu][r0+rr] = make_float4(-sg*L2E, sg*m*L2E, ww, ww*er); // transposed in LDS
    }
    __syncthreads();
    for (int rr = 0; rr < 32; rr += 8) {
      int u = tu*32 + r0 + rr, v = tv*32 + (tid & 31);
      P[u*Fq + v] = tl[r0+rr][tid & 31];          // coalesced write, [u][v]
    }
  } else {
    for (int i = tid; i < Bq*Sq; i += 256) {
      int b = i / Sq, t = i % Sq;
      iel[i] = (float)UNFq / (ts[b*(Sq+1)+t+1] - ts[b*(Sq+1)+t]); // 6/elapsed
    }
    for (int i = tid; i < 1024; i += 256) flags[i] = 0u;  // per-block phase flags
  }
}

// ---------------- K2: sensory synapse sums for all (b,t) ----------------
// (plain rcp here: x ~ N(0,1) tails make the paired-product risky)
__global__ __launch_bounds__(768) void k_sensory(
    const float* __restrict__ fv, const float* __restrict__ fi,
    const float* __restrict__ iw, const float* __restrict__ ib,
    const float4* __restrict__ Ps,
    float* __restrict__ wns, float* __restrict__ wds)
{
  __shared__ float xs[16][Fq];
  __shared__ float scr[12][8][33];
  int tid = threadIdx.x;
  int bt_tile = blockIdx.x >> 6;                  // 128 tiles of 16 (b,t)
  int ut = blockIdx.x & 63;                       // 64 u-tiles of 12
  int u0 = ut * 12, bt0 = bt_tile * 16;
  {
    float wv = iw[tid], bv = ib[tid];
    for (int j = 0; j < 16; ++j) {
      int bt = bt0 + j, b = bt >> 5, t = bt & 31;
      float raw = (tid < VFq) ? fv[(b*Sq + t)*VFq + tid]
                              : fi[(b*Sq + t)*IFq + (tid - VFq)];
      xs[j][tid] = raw * wv + bv;
    }
  }
  __syncthreads();
  int w = tid >> 6, l = tid & 63;
  const float4* P = Ps + (u0 + w)*Fq;
  #pragma unroll
  for (int pass = 0; pass < 4; ++pass) {
    float num[4], den[4];
    #pragma unroll
    for (int q = 0; q < 4; ++q) { num[q] = 0.f; den[q] = 0.f; }
    for (int i = 0; i < 12; ++i) {
      int f = l + 64*i;
      float4 p = P[f];
      #pragma unroll
      for (int q = 0; q < 4; ++q) {
        float arg = fmaf(p.x, xs[4*pass + q][f], p.y);
        float e = __builtin_amdgcn_exp2f(arg);
        float r = __builtin_amdgcn_rcpf(1.0f + e);  // sigmoid
        den[q] = fmaf(p.z, r, den[q]);
        num[q] = fmaf(p.w, r, num[q]);
      }
    }
    #pragma unroll
    for (int q = 0; q < 4; ++q) {
      num[q] = dpp_add<0xB1>(num[q]); den[q] = dpp_add<0xB1>(den[q]);
      num[q] = dpp_add<0x4E>(num[q]); den[q] = dpp_add<0x4E>(den[q]);
      num[q] = swz_add4(num[q]);      den[q] = swz_add4(den[q]);
    }
    if ((l & 7) == 0) {
      int rep = l >> 3;
      #pragma unroll
      for (int q = 0; q < 4; ++q) {
        scr[w][rep][4*pass + q] = num[q];
        scr[w][rep][16 + 4*pass + q] = den[q];
      }
    }
    __builtin_amdgcn_sched_barrier(0);
  }
  __syncthreads();
  if (tid < 192) {
    int u = tid >> 4, j = tid & 15;
    float nt = 0.f, dt = 0.f;
    #pragma unroll
    for (int rep = 0; rep < 8; ++rep) { nt += scr[u][rep][j]; dt += scr[u][rep][16+j]; }
    int bt = bt0 + j, b = bt >> 5, t = bt & 31;
    wns[(t*Bq + b)*Uq + (u0 + u)] = nt;
    wds[(t*Bq + b)*Uq + (u0 + u)] = dt;
  }
}

// ---------------- K3: recurrent unfolds (persistent, merged phase) ----------------
// 256 blocks = 4 groups(16 b) x 64 u-tiles(12 u), 1 block/CU, 12 waves.
// Wave w <-> target u = u0+w; full 768-v P-row in 48 VGPRs.
// R8 restructure: per phase ONE poll + ONE gather + 4 compute passes (4 j each,
// paired-rcp: 2 sigmoids share one v_rcp; safe since |v|<~1.5, sigma<=8 ->
// pair product <= 2^54) + ONE merged tail + ONE flag. 3 syncthreads/phase
// (R6 had 6 syncs, 2 polls, 2 gathers, 2 tails -> 5.1us/phase exposed).
// Single flag has zero slack (posted phase-end, needed next phase-start) --
// traded against the removed overhead.
// VGPR budget 84 (=512/6, LDS-derived 6 w/EU target; waves_per_eu attrs are
// not honored R3/R4). Live set ~76 by construction: 4-j passes,
// sched_barrier(0) between passes. Spills => 38 GB scratch churn (R3).
__global__ __launch_bounds__(768)
void k_recurrent(
    const float4* __restrict__ Pr,
    const float* __restrict__ wns, const float* __restrict__ wds,
    float* __restrict__ vg, const float* __restrict__ iel,
    unsigned* __restrict__ flags,
    const float* __restrict__ gleak, const float* __restrict__ vleak,
    const float* __restrict__ cm, const float* __restrict__ ow,
    const float* __restrict__ ob, float* __restrict__ hout)
{
  __shared__ float4 vvP[4][Uq];         // 48 KiB: panel p holds j=4p..4p+3
  __shared__ float2 scr2[12][8][17];    // 12.75 KiB cross-lane reduce scratch
  __shared__ float sinv[16][Sq];        // 2 KiB
  __shared__ float sgl[12], sglvl[12], scm[12], sow[12], sob[12];
  int tid = threadIdx.x;
  int g = blockIdx.x >> 6;              // group 0..3 (16 batches each)
  int ut = blockIdx.x & 63;             // u-tile 0..63
  int u0 = ut*12, b0 = g*16;
  if (tid < 512) { int j = tid >> 5, t = tid & 31; sinv[j][t] = iel[(b0+j)*Sq + t]; }
  if (tid < 12) {
    float gl0 = gleak[u0+tid];
    sgl[tid] = gl0; sglvl[tid] = gl0 * vleak[u0+tid];
    scm[tid] = cm[u0+tid]; sow[tid] = ow[u0+tid]; sob[tid] = ob[u0+tid];
  }
  #pragma unroll
  for (int q = 0; q < 4; ++q) vvP[q][tid] = make_float4(0.f, 0.f, 0.f, 0.f);
  int w = tid >> 6, l = tid & 63;
  float4 Prg[12];                       // entire P-row slice in registers (48 VGPRs)
  #pragma unroll
  for (int i = 0; i < 12; ++i) Prg[i] = Pr[(u0 + w)*Uq + l + 64*i];
  __syncthreads();
  int uu = tid >> 4, jj = tid & 15;     // tail mapping (tid<192)
  int p = 1;                            // phase 1..192
  for (int t = 0; t < Sq; ++t) {
    float wn_r = 0.f, wd_r = 0.f;
    if (tid < 192) {
      wn_r = wns[(t*Bq + b0 + jj)*Uq + u0 + uu];
      wd_r = wds[(t*Bq + b0 + jj)*Uq + u0 + uu];
    }
    for (int k = 0; k < UNFq; ++k, ++p) {
      int sp = p & 1, rp = sp ^ 1;      // store parity / reload parity
      // ---- single poll + gather of full state(p-1) ----
      if (p > 1) {
        const unsigned* f = flags + g*64 + l;   // every wave polls all 64 flags
        unsigned tgt = (unsigned)(p - 1);
        while (true) {
          unsigned vf = __hip_atomic_load(f, __ATOMIC_RELAXED, __HIP_MEMORY_SCOPE_AGENT);
          if (__ballot(vf < tgt) == 0ull) break;
          __builtin_amdgcn_s_sleep(1);
        }
        const unsigned long long* src =
            (const unsigned long long*)(vg + ((rp*4 + g)*Uq + tid)*16);
        float2 tmp[8];
        #pragma unroll
        for (int q = 0; q < 8; ++q) {
          unsigned long long uq = __hip_atomic_load(src + q, __ATOMIC_RELAXED,
                                                    __HIP_MEMORY_SCOPE_AGENT);
          tmp[q] = __builtin_bit_cast(float2, uq);
        }
        #pragma unroll
        for (int q = 0; q < 4; ++q)
          vvP[q][tid] = make_float4(tmp[2*q].x, tmp[2*q].y, tmp[2*q+1].x, tmp[2*q+1].y);
      }
      __syncthreads();                  // [sync 1] panels ready (or initial zeros)
      // ---- compute: 4 passes of 4 j, paired-rcp sigmoid ----
      #pragma unroll
      for (int q = 0; q < 4; ++q) {
        float num[4], den[4];
        #pragma unroll
        for (int qq = 0; qq < 4; ++qq) { num[qq] = 0.f; den[qq] = 0.f; }
        #pragma unroll
        for (int i = 0; i < 12; ++i) {
          int v = l + 64*i;
          float4 pp = Prg[i];
          float4 y = vvP[q][v];         // ds_read_b128
          float e0 = 1.0f + __builtin_amdgcn_exp2f(fmaf(pp.x, y.x, pp.y));
          float e1 = 1.0f + __builtin_amdgcn_exp2f(fmaf(pp.x, y.y, pp.y));
          float e2 = 1.0f + __builtin_amdgcn_exp2f(fmaf(pp.x, y.z, pp.y));
          float e3 = 1.0f + __builtin_amdgcn_exp2f(fmaf(pp.x, y.w, pp.y));
          float r01 = __builtin_amdgcn_rcpf(e0 * e1);
          float r23 = __builtin_amdgcn_rcpf(e2 * e3);
          float s0 = r01 * e1, s1 = r01 * e0;   // 1/e0, 1/e1
          float s2 = r23 * e3, s3 = r23 * e2;
          den[0] = fmaf(pp.z, s0, den[0]);
          num[0] = fmaf(pp.w, s0, num[0]);
          den[1] = fmaf(pp.z, s1, den[1]);
          num[1] = fmaf(pp.w, s1, num[1]);
          den[2] = fmaf(pp.z, s2, den[2]);
          num[2] = fmaf(pp.w, s2, num[2]);
          den[3] = fmaf(pp.z, s3, den[3]);
          num[3] = fmaf(pp.w, s3, num[3]);
        }
        #pragma unroll
        for (int qq = 0; qq < 4; ++qq) {
          num[qq] = dpp_add<0xB1>(num[qq]); den[qq] = dpp_add<0xB1>(den[qq]);
          num[qq] = dpp_add<0x4E>(num[qq]); den[qq] = dpp_add<0x4E>(den[qq]);
          num[qq] = swz_add4(num[qq]);      den[qq] = swz_add4(den[qq]);
        }
        if ((l & 7) == 0) {
          int r = l >> 3;
          #pragma unroll
          for (int qq = 0; qq < 4; ++qq)
            scr2[w][r][4*q + qq] = make_float2(num[qq], den[qq]);
        }
        __builtin_amdgcn_sched_barrier(0);  // keep passes sequential (reg pressure)
      }
      __syncthreads();                  // [sync 2] scr2 complete
      // ---- merged tail: ODE for all (12u x 16j) ----
      if (tid < 192) {
        float nt = wn_r, dt = wd_r;
        #pragma unroll
        for (int r = 0; r < 8; ++r) { float2 s = scr2[uu][r][jj]; nt += s.x; dt += s.y; }
        float cmt = scm[uu] * sinv[jj][t];
        const float* vrow = (const float*)&vvP[jj >> 2][u0 + uu];
        float vold = vrow[jj & 3];
        float vnew = (cmt*vold + sglvl[uu] + nt)
                   * __builtin_amdgcn_rcpf(cmt + sgl[uu] + dt + 1e-8f);
        __hip_atomic_store(&vg[((sp*4 + g)*Uq + u0 + uu)*16 + jj], vnew,
                           __ATOMIC_RELAXED, __HIP_MEMORY_SCOPE_AGENT);
        if (k == UNFq-1)
          hout[((b0 + jj)*Sq + t)*Uq + u0 + uu] = fmaf(vnew, sow[uu], sob[uu]);
      }
      __builtin_amdgcn_s_waitcnt(0);    // each wave drains its stores
      __syncthreads();                  // [sync 3] state globally visible
      if (tid == 0)                     // single contention-free signal
        __hip_atomic_store(&flags[g*64 + ut], (unsigned)p,
                           __ATOMIC_RELAXED, __HIP_MEMORY_SCOPE_AGENT);
    }
  }
}

// ---------------- K4: regressor head ----------------
__global__ __launch_bounds__(128) void k_head(
    const float* __restrict__ hseq, const float* __restrict__ W1,
    const float* __restrict__ b1, const float* __restrict__ W2,
    const float* __restrict__ b2, float* __restrict__ pose)
{
  __shared__ float h[Uq];
  __shared__ float x1[128];
  int bt = blockIdx.x, tid = threadIdx.x;
  for (int j = 0; j < 6; ++j) h[tid + 128*j] = hseq[bt*Uq + tid + 128*j];
  __syncthreads();
  float acc = b1[tid];
  for (int f = 0; f < Uq; ++f) acc = fmaf(h[f], W1[f*128 + tid], acc);
  x1[tid] = acc > 0.f ? acc : 0.1f*acc;            // LeakyReLU(0.1); h0 == 0
  __syncthreads();
  if (tid < 6) {
    float a2 = b2[tid];
    #pragma unroll
    for (int c = 0; c < 128; ++c) a2 = fmaf(x1[c], W2[c*6 + tid], a2);
    pose[bt*6 + tid] = a2;
  }
}

extern "C" void kernel_launch(void* const* d_in, const int* in_sizes, int n_in,
                              void* d_out, int out_size, void* d_ws, size_t ws_size,
                              hipStream_t stream) {
  const float* fv   = (const float*)d_in[0];
  const float* fi   = (const float*)d_in[2];
  const float* ts   = (const float*)d_in[4];
  const float* iw   = (const float*)d_in[5];
  const float* ibb  = (const float*)d_in[6];
  const float* smu  = (const float*)d_in[7];
  const float* ssig = (const float*)d_in[8];
  const float* sw   = (const float*)d_in[9];
  const float* ser  = (const float*)d_in[10];
  const float* rmu  = (const float*)d_in[11];
  const float* rsig = (const float*)d_in[12];
  const float* rw   = (const float*)d_in[13];
  const float* rer  = (const float*)d_in[14];
  const float* gl   = (const float*)d_in[15];
  const float* vl   = (const float*)d_in[16];
  const float* cm   = (const float*)d_in[17];
  const float* ow   = (const float*)d_in[18];
  const float* ob   = (const float*)d_in[19];
  const float* W1   = (const float*)d_in[20];
  const float* b1   = (const float*)d_in[21];
  const float* W2   = (const float*)d_in[22];
  const float* b2   = (const float*)d_in[23];

  float* pose = (float*)d_out;                 // (B,1,S,6) = 12288 floats
  float* hseq = (float*)d_out + Bq*Sq*6;       // (B,S,U)   = 1572864 floats

  float* ws = (float*)d_ws;
  float4* Ps = (float4*)ws;                    // 2,359,296 floats
  float4* Pr = (float4*)(ws + 2359296);        // 2,359,296
  float* wns = ws + 4718592;                   // 1,572,864
  float* wds = ws + 6291456;                   // 1,572,864
  float* vg  = ws + 7864320;                   // 98,304 (2 par x 4 g x 768 u x 16 j)
  float* iel = ws + 7962624;                   // 2,048
  unsigned* flags = (unsigned*)(ws + 7964672); // 1,024 (256 used)

  k_prep<<<1153, 256, 0, stream>>>(smu, ssig, sw, ser, rmu, rsig, rw, rer,
                                   ts, Ps, Pr, iel, flags);
  k_sensory<<<8192, 768, 0, stream>>>(fv, fi, iw, ibb, Ps, wns, wds);
  k_recurrent<<<256, 768, 0, stream>>>(Pr, wns, wds, vg, iel, flags,
                                       gl, vl, cm, ow, ob, hseq);
  k_head<<<2048, 128, 0, stream>>>(hseq, W1, b1, W2, b2, pose);
}

// Round 9
// 2424.960 us; speedup vs baseline: 1.3555x; 1.3555x over previous
//
#include <hip/hip_runtime.h>

#define Bq 64
#define Sq 32
#define VFq 512
#define IFq 256
#define Fq 768
#define Uq 768
#define UNFq 6
#define L2E 1.44269504088896340736f
typedef unsigned long long ull;

template <int CTRL>
__device__ __forceinline__ float dpp_add(float x) {
  int t = __builtin_amdgcn_update_dpp(0, __builtin_bit_cast(int, x), CTRL, 0xF, 0xF, true);
  return x + __builtin_bit_cast(float, t);
}
__device__ __forceinline__ float swz_add4(float x) {
  int t = __builtin_amdgcn_ds_swizzle(__builtin_bit_cast(int, x), 0x101F); // xor 4
  return x + __builtin_bit_cast(float, t);
}

// ---------------- K1: fold+transpose params, init misc ----------------
// P[u][v] = float4(-sigma*log2e, sigma*mu*log2e, w, w*erev)  (u = target, v = source)
__global__ __launch_bounds__(256) void k_prep(
    const float* __restrict__ smu, const float* __restrict__ ssig,
    const float* __restrict__ sw,  const float* __restrict__ ser,
    const float* __restrict__ rmu, const float* __restrict__ rsig,
    const float* __restrict__ rw,  const float* __restrict__ rer,
    const float* __restrict__ ts,
    float4* __restrict__ Ps, float4* __restrict__ Pr,
    float* __restrict__ iel, unsigned* __restrict__ flags)
{
  int bid = blockIdx.x, tid = threadIdx.x;
  if (bid < 1152) {
    int set = bid / 576, tile = bid % 576;
    int tv = tile / 24, tu = tile % 24;
    const float* Amu = set ? rmu : smu;
    const float* Asg = set ? rsig : ssig;
    const float* Aw  = set ? rw  : sw;
    const float* Aer = set ? rer : ser;
    float4* P = set ? Pr : Ps;
    __shared__ float4 tl[32][33];
    int cu = tid & 31, r0 = tid >> 5;            // 32 cols x 8 rows
    for (int rr = 0; rr < 32; rr += 8) {
      int v = tv*32 + r0 + rr, u = tu*32 + cu;
      int idx = v*Uq + u;                         // source-major input layout
      float sg = Asg[idx], m = Amu[idx], ww = Aw[idx], er = Aer[idx];
      tl[cu][r0+rr] = make_float4(-sg*L2E, sg*m*L2E, ww, ww*er); // transposed in LDS
    }
    __syncthreads();
    for (int rr = 0; rr < 32; rr += 8) {
      int u = tu*32 + r0 + rr, v = tv*32 + (tid & 31);
      P[u*Fq + v] = tl[r0+rr][tid & 31];          // coalesced write, [u][v]
    }
  } else {
    for (int i = tid; i < Bq*Sq; i += 256) {
      int b = i / Sq, t = i % Sq;
      iel[i] = (float)UNFq / (ts[b*(Sq+1)+t+1] - ts[b*(Sq+1)+t]); // 6/elapsed
    }
    for (int i = tid; i < 1024; i += 256) flags[i] = 0u;  // per-block phase flags
  }
}

// ---------------- K2: sensory synapse sums for all (b,t) ----------------
__global__ __launch_bounds__(768) void k_sensory(
    const float* __restrict__ fv, const float* __restrict__ fi,
    const float* __restrict__ iw, const float* __restrict__ ib,
    const float4* __restrict__ Ps,
    float* __restrict__ wns, float* __restrict__ wds)
{
  __shared__ float xs[16][Fq];
  __shared__ float scr[12][8][33];
  int tid = threadIdx.x;
  int bt_tile = blockIdx.x >> 6;                  // 128 tiles of 16 (b,t)
  int ut = blockIdx.x & 63;                       // 64 u-tiles of 12
  int u0 = ut * 12, bt0 = bt_tile * 16;
  {
    float wv = iw[tid], bv = ib[tid];
    for (int j = 0; j < 16; ++j) {
      int bt = bt0 + j, b = bt >> 5, t = bt & 31;
      float raw = (tid < VFq) ? fv[(b*Sq + t)*VFq + tid]
                              : fi[(b*Sq + t)*IFq + (tid - VFq)];
      xs[j][tid] = raw * wv + bv;
    }
  }
  __syncthreads();
  int w = tid >> 6, l = tid & 63;
  const float4* P = Ps + (u0 + w)*Fq;
  #pragma unroll
  for (int pass = 0; pass < 4; ++pass) {
    float num[4], den[4];
    #pragma unroll
    for (int q = 0; q < 4; ++q) { num[q] = 0.f; den[q] = 0.f; }
    for (int i = 0; i < 12; ++i) {
      int f = l + 64*i;
      float4 p = P[f];
      #pragma unroll
      for (int q = 0; q < 4; ++q) {
        float arg = fmaf(p.x, xs[4*pass + q][f], p.y);
        float e = __builtin_amdgcn_exp2f(arg);
        float r = __builtin_amdgcn_rcpf(1.0f + e);  // sigmoid
        den[q] = fmaf(p.z, r, den[q]);
        num[q] = fmaf(p.w, r, num[q]);
      }
    }
    #pragma unroll
    for (int q = 0; q < 4; ++q) {
      num[q] = dpp_add<0xB1>(num[q]); den[q] = dpp_add<0xB1>(den[q]);
      num[q] = dpp_add<0x4E>(num[q]); den[q] = dpp_add<0x4E>(den[q]);
      num[q] = swz_add4(num[q]);      den[q] = swz_add4(den[q]);
    }
    if ((l & 7) == 0) {
      int rep = l >> 3;
      #pragma unroll
      for (int q = 0; q < 4; ++q) {
        scr[w][rep][4*pass + q] = num[q];
        scr[w][rep][16 + 4*pass + q] = den[q];
      }
    }
    __builtin_amdgcn_sched_barrier(0);
  }
  __syncthreads();
  if (tid < 192) {
    int u = tid >> 4, j = tid & 15;
    float nt = 0.f, dt = 0.f;
    #pragma unroll
    for (int rep = 0; rep < 8; ++rep) { nt += scr[u][rep][j]; dt += scr[u][rep][16+j]; }
    int bt = bt0 + j, b = bt >> 5, t = bt & 31;
    wns[(t*Bq + b)*Uq + (u0 + u)] = nt;
    wds[(t*Bq + b)*Uq + (u0 + u)] = dt;
  }
}

// ---------------- K3: recurrent unfolds (persistent, prefetch pipeline) --------
// 256 blocks = 4 groups(16 b) x 64 u-tiles(12 u), 1 block/CU, 12 waves.
// Wave w <-> target u = u0+w; full 768-v P-row in 48 VGPRs.
// Half-streams (8 j each) are independent; per half-step X (half h):
//   pass0(h)                              [~1.2us]
//   poll peers done X-1 (slack = pass0)   [usually instant]
//   issue 4xb64 gather loads (input X+1, half 1-h) -- NO wait
//   pass1(h)                              [loads land in background]
//   write gathered regs -> panels(1-h)
//   sync2; tail h (ODE, vg store, waitcnt); sync3; signal X
// Safety: poll-at-X precedes tail-at-X, so a block can only overwrite its
// half-h slot after all peers completed X-1 (whose gather of the old value
// happened before their signal) -> single buffer per half, no parity.
// 4 syncs/phase (R6: 6), gather+poll off the critical path.
// VGPR budget 84 (LDS<64K -> 6 w/EU target; attrs not honored R3/R4); gather
// regs live only across pass1 -> ~80 live, no spills (tripwire: WRITE_SIZE).
__global__ __launch_bounds__(768)
void k_recurrent(
    const float4* __restrict__ Pr,
    const float* __restrict__ wns, const float* __restrict__ wds,
    float* __restrict__ vg, const float* __restrict__ iel,
    unsigned* __restrict__ flags,
    const float* __restrict__ gleak, const float* __restrict__ vleak,
    const float* __restrict__ cm, const float* __restrict__ ow,
    const float* __restrict__ ob, float* __restrict__ hout)
{
  __shared__ float4 vvP[4][Uq];         // 48 KiB: panels 2h,2h+1 = half h's j-quads
  __shared__ float2 scr2[12][8][9];     // 6.75 KiB reduce scratch (one half)
  __shared__ float sinv[16][Sq];        // 2 KiB
  __shared__ float swn[2][96], swd[2][96];
  __shared__ float sgl[12], sglvl[12], scm[12], sow[12], sob[12];
  int tid = threadIdx.x;
  int g = blockIdx.x >> 6;              // group 0..3 (16 batches each)
  int ut = blockIdx.x & 63;             // u-tile 0..63
  int u0 = ut*12, b0 = g*16;
  if (tid < 512) { int j = tid >> 5, t = tid & 31; sinv[j][t] = iel[(b0+j)*Sq + t]; }
  if (tid < 12) {
    float gl0 = gleak[u0+tid];
    sgl[tid] = gl0; sglvl[tid] = gl0 * vleak[u0+tid];
    scm[tid] = cm[u0+tid]; sow[tid] = ow[u0+tid]; sob[tid] = ob[u0+tid];
  }
  #pragma unroll
  for (int q = 0; q < 4; ++q) vvP[q][tid] = make_float4(0.f, 0.f, 0.f, 0.f);
  int w = tid >> 6, l = tid & 63;
  float4 Prg[12];                       // entire P-row slice in registers (48 VGPRs)
  #pragma unroll
  for (int i = 0; i < 12; ++i) Prg[i] = Pr[(u0 + w)*Uq + l + 64*i];
  __syncthreads();
  int uu8 = tid >> 3, jv = tid & 7;     // tail mapping (tid<96)
  for (int t = 0; t < Sq; ++t) {
    if (tid < 96) {                     // stash this t's sensory sums in LDS
      swn[0][tid] = wns[(t*Bq + b0 + jv)*Uq + u0 + uu8];
      swd[0][tid] = wds[(t*Bq + b0 + jv)*Uq + u0 + uu8];
      swn[1][tid] = wns[(t*Bq + b0 + 8 + jv)*Uq + u0 + uu8];
      swd[1][tid] = wds[(t*Bq + b0 + 8 + jv)*Uq + u0 + uu8];
    }
    for (int k = 0; k < UNFq; ++k) {
      int p = t*UNFq + k;               // phase 0..191
      #pragma unroll
      for (int h = 0; h < 2; ++h) {
        int hp = 1 - h;
        float num0[4], den0[4], num1[4], den1[4];
        // ---- pass 0: j-quad 0 of half h ----
        #pragma unroll
        for (int q = 0; q < 4; ++q) { num0[q] = 0.f; den0[q] = 0.f; }
        #pragma unroll
        for (int i = 0; i < 12; ++i) {
          int v = l + 64*i;
          float4 pp = Prg[i];
          float4 y = vvP[2*h][v];
          float r0 = __builtin_amdgcn_rcpf(1.0f + __builtin_amdgcn_exp2f(fmaf(pp.x, y.x, pp.y)));
          float r1 = __builtin_amdgcn_rcpf(1.0f + __builtin_amdgcn_exp2f(fmaf(pp.x, y.y, pp.y)));
          float r2 = __builtin_amdgcn_rcpf(1.0f + __builtin_amdgcn_exp2f(fmaf(pp.x, y.z, pp.y)));
          float r3 = __builtin_amdgcn_rcpf(1.0f + __builtin_amdgcn_exp2f(fmaf(pp.x, y.w, pp.y)));
          den0[0] = fmaf(pp.z, r0, den0[0]); num0[0] = fmaf(pp.w, r0, num0[0]);
          den0[1] = fmaf(pp.z, r1, den0[1]); num0[1] = fmaf(pp.w, r1, num0[1]);
          den0[2] = fmaf(pp.z, r2, den0[2]); num0[2] = fmaf(pp.w, r2, num0[2]);
          den0[3] = fmaf(pp.z, r3, den0[3]); num0[3] = fmaf(pp.w, r3, num0[3]);
        }
        #pragma unroll
        for (int q = 0; q < 4; ++q) {
          num0[q] = dpp_add<0xB1>(num0[q]); den0[q] = dpp_add<0xB1>(den0[q]);
          num0[q] = dpp_add<0x4E>(num0[q]); den0[q] = dpp_add<0x4E>(den0[q]);
          num0[q] = swz_add4(num0[q]);      den0[q] = swz_add4(den0[q]);
        }
        if ((l & 7) == 0) {
          int r = l >> 3;
          #pragma unroll
          for (int q = 0; q < 4; ++q) scr2[w][r][q] = make_float2(num0[q], den0[q]);
        }
        __builtin_amdgcn_sched_barrier(0);
        // ---- poll (slack = pass0) + issue gather loads for half hp ----
        ull ga0 = 0, ga1 = 0, ga2 = 0, ga3 = 0;
        bool do_g = !(p == 0 && h == 0);
        if (do_g) {
          const unsigned* f = flags + hp*256 + g*64 + l;  // every wave polls
          unsigned tgt = (unsigned)(p + h);               // h=0: p, h=1: p+1
          while (true) {
            unsigned vf = __hip_atomic_load(f, __ATOMIC_RELAXED, __HIP_MEMORY_SCOPE_AGENT);
            if (__ballot(vf < tgt) == 0ull) break;
            __builtin_amdgcn_s_sleep(1);
          }
          const ull* src = (const ull*)(vg + (hp*4 + g)*Uq*8) + tid*4;
          ga0 = __hip_atomic_load(src + 0, __ATOMIC_RELAXED, __HIP_MEMORY_SCOPE_AGENT);
          ga1 = __hip_atomic_load(src + 1, __ATOMIC_RELAXED, __HIP_MEMORY_SCOPE_AGENT);
          ga2 = __hip_atomic_load(src + 2, __ATOMIC_RELAXED, __HIP_MEMORY_SCOPE_AGENT);
          ga3 = __hip_atomic_load(src + 3, __ATOMIC_RELAXED, __HIP_MEMORY_SCOPE_AGENT);
        }
        __builtin_amdgcn_sched_barrier(0);
        // ---- pass 1: j-quad 1 of half h (gather loads land here) ----
        #pragma unroll
        for (int q = 0; q < 4; ++q) { num1[q] = 0.f; den1[q] = 0.f; }
        #pragma unroll
        for (int i = 0; i < 12; ++i) {
          int v = l + 64*i;
          float4 pp = Prg[i];
          float4 y = vvP[2*h+1][v];
          float r0 = __builtin_amdgcn_rcpf(1.0f + __builtin_amdgcn_exp2f(fmaf(pp.x, y.x, pp.y)));
          float r1 = __builtin_amdgcn_rcpf(1.0f + __builtin_amdgcn_exp2f(fmaf(pp.x, y.y, pp.y)));
          float r2 = __builtin_amdgcn_rcpf(1.0f + __builtin_amdgcn_exp2f(fmaf(pp.x, y.z, pp.y)));
          float r3 = __builtin_amdgcn_rcpf(1.0f + __builtin_amdgcn_exp2f(fmaf(pp.x, y.w, pp.y)));
          den1[0] = fmaf(pp.z, r0, den1[0]); num1[0] = fmaf(pp.w, r0, num1[0]);
          den1[1] = fmaf(pp.z, r1, den1[1]); num1[1] = fmaf(pp.w, r1, num1[1]);
          den1[2] = fmaf(pp.z, r2, den1[2]); num1[2] = fmaf(pp.w, r2, num1[2]);
          den1[3] = fmaf(pp.z, r3, den1[3]); num1[3] = fmaf(pp.w, r3, num1[3]);
        }
        #pragma unroll
        for (int q = 0; q < 4; ++q) {
          num1[q] = dpp_add<0xB1>(num1[q]); den1[q] = dpp_add<0xB1>(den1[q]);
          num1[q] = dpp_add<0x4E>(num1[q]); den1[q] = dpp_add<0x4E>(den1[q]);
          num1[q] = swz_add4(num1[q]);      den1[q] = swz_add4(den1[q]);
        }
        if ((l & 7) == 0) {
          int r = l >> 3;
          #pragma unroll
          for (int q = 0; q < 4; ++q) scr2[w][r][4+q] = make_float2(num1[q], den1[q]);
        }
        // ---- write gathered state into the other half's panels ----
        if (do_g) {
          float2 t0 = __builtin_bit_cast(float2, ga0);
          float2 t1 = __builtin_bit_cast(float2, ga1);
          float2 t2 = __builtin_bit_cast(float2, ga2);
          float2 t3 = __builtin_bit_cast(float2, ga3);
          vvP[2*hp+0][tid] = make_float4(t0.x, t0.y, t1.x, t1.y);
          vvP[2*hp+1][tid] = make_float4(t2.x, t2.y, t3.x, t3.y);
        }
        __syncthreads();                // [sync2] scr2 + panels(hp) ready
        // ---- tail: ODE for (12u x 8j) of half h ----
        if (tid < 96) {
          float nt = swn[h][tid], dt = swd[h][tid];
          #pragma unroll
          for (int r = 0; r < 8; ++r) { float2 s = scr2[uu8][r][jv]; nt += s.x; dt += s.y; }
          int jh = h*8 + jv;
          float cmt = scm[uu8] * sinv[jh][t];
          const float* vrow = (const float*)&vvP[2*h + (jv >> 2)][u0 + uu8];
          float vold = vrow[jv & 3];
          float vnew = (cmt*vold + sglvl[uu8] + nt)
                     * __builtin_amdgcn_rcpf(cmt + sgl[uu8] + dt + 1e-8f);
          __hip_atomic_store(&vg[(h*4 + g)*Uq*8 + (u0 + uu8)*8 + jv], vnew,
                             __ATOMIC_RELAXED, __HIP_MEMORY_SCOPE_AGENT);
          if (k == UNFq-1)
            hout[((b0 + jh)*Sq + t)*Uq + u0 + uu8] = fmaf(vnew, sow[uu8], sob[uu8]);
        }
        __builtin_amdgcn_s_waitcnt(0);  // drain tail stores (others: no-op)
        __syncthreads();                // [sync3] state globally visible
        if (tid == 0)                   // contention-free signal
          __hip_atomic_store(&flags[h*256 + g*64 + ut], (unsigned)(p + 1),
                             __ATOMIC_RELAXED, __HIP_MEMORY_SCOPE_AGENT);
      }
    }
  }
}

// ---------------- K4: regressor head ----------------
__global__ __launch_bounds__(128) void k_head(
    const float* __restrict__ hseq, const float* __restrict__ W1,
    const float* __restrict__ b1, const float* __restrict__ W2,
    const float* __restrict__ b2, float* __restrict__ pose)
{
  __shared__ float h[Uq];
  __shared__ float x1[128];
  int bt = blockIdx.x, tid = threadIdx.x;
  for (int j = 0; j < 6; ++j) h[tid + 128*j] = hseq[bt*Uq + tid + 128*j];
  __syncthreads();
  float acc = b1[tid];
  for (int f = 0; f < Uq; ++f) acc = fmaf(h[f], W1[f*128 + tid], acc);
  x1[tid] = acc > 0.f ? acc : 0.1f*acc;            // LeakyReLU(0.1); h0 == 0
  __syncthreads();
  if (tid < 6) {
    float a2 = b2[tid];
    #pragma unroll
    for (int c = 0; c < 128; ++c) a2 = fmaf(x1[c], W2[c*6 + tid], a2);
    pose[bt*6 + tid] = a2;
  }
}

extern "C" void kernel_launch(void* const* d_in, const int* in_sizes, int n_in,
                              void* d_out, int out_size, void* d_ws, size_t ws_size,
                              hipStream_t stream) {
  const float* fv   = (const float*)d_in[0];
  const float* fi   = (const float*)d_in[2];
  const float* ts   = (const float*)d_in[4];
  const float* iw   = (const float*)d_in[5];
  const float* ibb  = (const float*)d_in[6];
  const float* smu  = (const float*)d_in[7];
  const float* ssig = (const float*)d_in[8];
  const float* sw   = (const float*)d_in[9];
  const float* ser  = (const float*)d_in[10];
  const float* rmu  = (const float*)d_in[11];
  const float* rsig = (const float*)d_in[12];
  const float* rw   = (const float*)d_in[13];
  const float* rer  = (const float*)d_in[14];
  const float* gl   = (const float*)d_in[15];
  const float* vl   = (const float*)d_in[16];
  const float* cm   = (const float*)d_in[17];
  const float* ow   = (const float*)d_in[18];
  const float* ob   = (const float*)d_in[19];
  const float* W1   = (const float*)d_in[20];
  const float* b1   = (const float*)d_in[21];
  const float* W2   = (const float*)d_in[22];
  const float* b2   = (const float*)d_in[23];

  float* pose = (float*)d_out;                 // (B,1,S,6) = 12288 floats
  float* hseq = (float*)d_out + Bq*Sq*6;       // (B,S,U)   = 1572864 floats

  float* ws = (float*)d_ws;
  float4* Ps = (float4*)ws;                    // 2,359,296 floats
  float4* Pr = (float4*)(ws + 2359296);        // 2,359,296
  float* wns = ws + 4718592;                   // 1,572,864
  float* wds = ws + 6291456;                   // 1,572,864
  float* vg  = ws + 7864320;                   // 49,152 (2 half x 4 g x 768 u x 8 j)
  float* iel = ws + 7962624;                   // 2,048
  unsigned* flags = (unsigned*)(ws + 7964672); // 512 used (2 half x 4 g x 64)

  k_prep<<<1153, 256, 0, stream>>>(smu, ssig, sw, ser, rmu, rsig, rw, rer,
                                   ts, Ps, Pr, iel, flags);
  k_sensory<<<8192, 768, 0, stream>>>(fv, fi, iw, ibb, Ps, wns, wds);
  k_recurrent<<<256, 768, 0, stream>>>(Pr, wns, wds, vg, iel, flags,
                                       gl, vl, cm, ow, ob, hseq);
  k_head<<<2048, 128, 0, stream>>>(hseq, W1, b1, W2, b2, pose);
}